// Round 1
// baseline (542.025 us; speedup 1.0000x reference)
//
#include <hip/hip_runtime.h>

typedef __attribute__((ext_vector_type(8))) short short8;
typedef __attribute__((ext_vector_type(4))) float f32x4;

// ---- workspace layout (uint16 element offsets from ws base) ----
// LSTM weights stored as hi-plane then lo-plane (hi+lo bf16 ~= fp32).
#define OFF_BXO   64                        // obs Wih B-frags hi[8192]+lo[8192]
#define OFF_BHO   (OFF_BXO + 16384)         // obs Whh B-frags hi[16384]+lo[16384]
#define OFF_BXW   (OFF_BHO + 32768)         // wrf Wih B-frags hi[16384]+lo[16384]
#define OFF_BHW   (OFF_BXW + 32768)         // wrf Whh B-frags hi[16384]+lo[16384]
#define OFF_HW    (OFF_BHW + 32768)         // head weights bf16 (single)
#define OFF_BIASL (OFF_HW + 43008)          // fp32: lstm bias (bih+bhh) [2][256]
#define OFF_BIASH (OFF_BIASL + 1024)        // fp32: head biases [2][208]
#define OFF_FEAT  (OFF_BIASH + 832)         // feat hi [8192][128] + lo plane
// total ~2.3M uint16 = ~4.6 MB of ws

__device__ __forceinline__ float b2f(unsigned short u) {
    return __uint_as_float(((unsigned)u) << 16);
}
__device__ __forceinline__ unsigned short f2b(float f) {
    unsigned u = __float_as_uint(f);
    u += 0x7FFFu + ((u >> 16) & 1u);   // RNE
    return (unsigned short)(u >> 16);
}
__device__ __forceinline__ float ldin(const void* p, int idx, int isf) {
    return isf ? ((const float*)p)[idx] : b2f(((const unsigned short*)p)[idx]);
}
__device__ __forceinline__ float sigmoidf_(float x) {
    return __builtin_amdgcn_rcpf(1.0f + __expf(-x));
}
__device__ __forceinline__ float tanhf_(float x) {
    return 2.0f * __builtin_amdgcn_rcpf(1.0f + __expf(-2.0f * x)) - 1.0f;
}
__device__ __forceinline__ f32x4 MFMA(short8 a, short8 b, f32x4 c) {
    return __builtin_amdgcn_mfma_f32_16x16x32_bf16(a, b, c, 0, 0, 0);
}

// ---------------------------------------------------------------------------
// Kernel 0: dtype detector. Little-endian fp32: uint16[2i] is the LOW mantissa
// half (~uniform bits, P(bf16-exponent-field >= 192) = 25%). Genuine bf16
// N(0,1) data never has exponent >= 192. flag=1 means fp32.
// ---------------------------------------------------------------------------
__global__ __launch_bounds__(256) void detect_kernel(
    const unsigned short* __restrict__ X, int* __restrict__ flag)
{
    __shared__ int cnt[256];
    int c = 0;
    for (int i = threadIdx.x; i < 2048; i += 256) {
        unsigned short u = X[2 * i];   // EVEN half-word
        c += (((u >> 7) & 0xFF) >= 192);
    }
    cnt[threadIdx.x] = c;
    __syncthreads();
    if (threadIdx.x == 0) {
        int s = 0;
        for (int i = 0; i < 256; ++i) s += cnt[i];
        *flag = (s > 64) ? 1 : 0;
    }
}

// ---------------------------------------------------------------------------
// Kernel 1: weight prep. LSTM weights -> hi+lo bf16 pairs in MFMA B-fragment
// order; head weights -> single bf16; biases pre-summed in fp32.
// ---------------------------------------------------------------------------
__global__ __launch_bounds__(256) void prep_kernel(
    const void* oWih, const void* oWhh, const void* obih, const void* obhh,
    const void* wWih, const void* wWhh, const void* wbih, const void* wbhh,
    const void* fW1, const void* fb1, const void* fW2, const void* fb2,
    const void* fW3, const void* fb3,
    const void* oW1, const void* ob1, const void* oW2, const void* ob2,
    const void* oW3, const void* ob3,
    unsigned short* __restrict__ ws)
{
    const int isf = ((const int*)ws)[0];
    const int gid = blockIdx.x * 256 + threadIdx.x;
    const int gsz = gridDim.x * 256;

    unsigned short* BXO = ws + OFF_BXO;
    unsigned short* BHO = ws + OFF_BHO;
    unsigned short* BXW = ws + OFF_BXW;
    unsigned short* BHW = ws + OFF_BHW;
    unsigned short* HW  = ws + OFF_HW;

    // obs Wih: i = wave*2048 + nt*512 + lane*8 + j
    for (int i = gid; i < 8192; i += gsz) {
        int j = i & 7, lane = (i >> 3) & 63, nt = (i >> 9) & 3, wave = i >> 11;
        int g = wave * 64 + nt * 16 + (lane & 15);
        int k = ((lane >> 4) << 3) + j;
        float w = ldin(oWih, g * 32 + k, isf);
        unsigned short hi = f2b(w);
        BXO[i] = hi; BXO[8192 + i] = f2b(w - b2f(hi));
    }
    // obs Whh: i = wave*4096 + kt*2048 + nt*512 + lane*8 + j
    for (int i = gid; i < 16384; i += gsz) {
        int j = i & 7, lane = (i >> 3) & 63, nt = (i >> 9) & 3;
        int kt = (i >> 11) & 1, wave = i >> 12;
        int g = wave * 64 + nt * 16 + (lane & 15);
        int k = kt * 32 + ((lane >> 4) << 3) + j;
        float w = ldin(oWhh, g * 64 + k, isf);
        unsigned short hi = f2b(w);
        BHO[i] = hi; BHO[16384 + i] = f2b(w - b2f(hi));
    }
    // wrf Wih: i = kt2*8192 + wave*2048 + nt*512 + lane*8 + j (zero-pad k>=56)
    for (int i = gid; i < 16384; i += gsz) {
        int j = i & 7, lane = (i >> 3) & 63, nt = (i >> 9) & 3;
        int wave = (i >> 11) & 3, kt2 = i >> 13;
        int g = wave * 64 + nt * 16 + (lane & 15);
        int k = kt2 * 32 + ((lane >> 4) << 3) + j;
        float w = (k < 56) ? ldin(wWih, g * 56 + k, isf) : 0.f;
        unsigned short hi = f2b(w);
        BXW[i] = hi; BXW[16384 + i] = f2b(w - b2f(hi));
    }
    // wrf Whh
    for (int i = gid; i < 16384; i += gsz) {
        int j = i & 7, lane = (i >> 3) & 63, nt = (i >> 9) & 3;
        int kt = (i >> 11) & 1, wave = i >> 12;
        int g = wave * 64 + nt * 16 + (lane & 15);
        int k = kt * 32 + ((lane >> 4) << 3) + j;
        float w = ldin(wWhh, g * 64 + k, isf);
        unsigned short hi = f2b(w);
        BHW[i] = hi; BHW[16384 + i] = f2b(w - b2f(hi));
    }
    // head weights, plain row-major bf16
    for (int i = gid; i < 12288; i += gsz) HW[i]         = f2b(ldin(fW1, i, isf));
    for (int i = gid; i < 6144;  i += gsz) HW[12288 + i] = f2b(ldin(fW2, i, isf));
    for (int i = gid; i < 3072;  i += gsz) HW[18432 + i] = f2b(ldin(fW3, i, isf));
    for (int i = gid; i < 12288; i += gsz) HW[21504 + i] = f2b(ldin(oW1, i, isf));
    for (int i = gid; i < 6144;  i += gsz) HW[33792 + i] = f2b(ldin(oW2, i, isf));
    for (int i = gid; i < 3072;  i += gsz) HW[39936 + i] = f2b(ldin(oW3, i, isf));
    // lstm biases (bih+bhh), fp32
    float* BL = (float*)(ws + OFF_BIASL);
    for (int i = gid; i < 256; i += gsz) BL[i]       = ldin(obih, i, isf) + ldin(obhh, i, isf);
    for (int i = gid; i < 256; i += gsz) BL[256 + i] = ldin(wbih, i, isf) + ldin(wbhh, i, isf);
    // head biases, fp32: [fsp b1(96) b2(64) b3(48)][o3 ...]
    float* BB = (float*)(ws + OFF_BIASH);
    for (int i = gid; i < 96; i += gsz) BB[i]       = ldin(fb1, i, isf);
    for (int i = gid; i < 64; i += gsz) BB[96 + i]  = ldin(fb2, i, isf);
    for (int i = gid; i < 48; i += gsz) BB[160 + i] = ldin(fb3, i, isf);
    for (int i = gid; i < 96; i += gsz) BB[208 + i] = ldin(ob1, i, isf);
    for (int i = gid; i < 64; i += gsz) BB[304 + i] = ldin(ob2, i, isf);
    for (int i = gid; i < 48; i += gsz) BB[368 + i] = ldin(ob3, i, isf);
}

// ---------------------------------------------------------------------------
// Kernel 2: persistent-per-block LSTM, hi+lo bf16 everywhere (x, Wih, Whh, h)
// with 3-term MFMA products -> matmuls are ~fp32-exact. Block = 4 waves owns
// 16 batch rows (blocks 0..511 obs, 512..1023 wrf), 72 steps in 9 chunks of 8.
// LDS: 32 KB xbuf + 16 KB gates + 4 KB hfrag = 52 KB.
// ---------------------------------------------------------------------------
__global__ __launch_bounds__(256) void lstm_kernel(
    const void* __restrict__ Xo, const void* __restrict__ Xw,
    unsigned short* __restrict__ ws)
{
    __shared__ unsigned short xbuf[2][8][8][16][8];  // [hi/lo][t][ktile][m][j]
    __shared__ float gates[256][16];                 // [gate][n-in-block]
    __shared__ unsigned short hfrag[2][2][4][16][8]; // [hi/lo][kt][quad][m][j]

    const int tid  = threadIdx.x;
    const int wave = tid >> 6, lane = tid & 63;
    const int quad = lane >> 4, m16 = lane & 15;
    const bool isw = blockIdx.x >= 512;
    const int blk  = isw ? (int)blockIdx.x - 512 : (int)blockIdx.x;
    const int n0   = blk * 16;
    const int isf  = ((const int*)ws)[0];

    const void* x = isw ? Xw : Xo;
    const unsigned short* BX = ws + (isw ? OFF_BXW : OFF_BXO);
    const unsigned short* BH = ws + (isw ? OFF_BHW : OFF_BHO);
    const float* BL = (const float*)(ws + OFF_BIASL) + (isw ? 256 : 0);
    unsigned short* featH = ws + OFF_FEAT;
    unsigned short* featL = featH + 8192 * 128;
    const int C       = isw ? 56 : 32;
    const int Cpad    = isw ? 64 : 32;
    const int cshift  = isw ? 6 : 5;
    const int xloOff  = isw ? 16384 : 8192;   // lo-plane offset within BX
    const int featOff = isw ? 64 : 0;

    // --- B fragments (constant over all 72 steps) ---
    short8 BhH[2][4], BhL[2][4];
#pragma unroll
    for (int kt = 0; kt < 2; ++kt)
#pragma unroll
        for (int nt = 0; nt < 4; ++nt) {
            int idx = ((wave * 2 + kt) * 4 + nt) * 512 + lane * 8;
            BhH[kt][nt] = *(const short8*)&BH[idx];
            BhL[kt][nt] = *(const short8*)&BH[16384 + idx];
        }
    short8 BxH0[4], BxL0[4], BxH1[4], BxL1[4];
#pragma unroll
    for (int nt = 0; nt < 4; ++nt) {
        int idx = (wave * 4 + nt) * 512 + lane * 8;
        BxH0[nt] = *(const short8*)&BX[idx];
        BxL0[nt] = *(const short8*)&BX[xloOff + idx];
    }
    if (isw) {
#pragma unroll
        for (int nt = 0; nt < 4; ++nt) {
            int idx = (wave * 4 + nt) * 512 + lane * 8;
            BxH1[nt] = *(const short8*)&BX[8192 + idx];
            BxL1[nt] = *(const short8*)&BX[xloOff + 8192 + idx];
        }
    }

    // update phase: thread owns hidden unit j0 for 4 batch rows
    const int j0  = tid >> 2;
    const int nlo = (tid & 3) * 4;
    const float bias_i = BL[j0];
    const float bias_f = BL[j0 + 64];
    const float bias_g = BL[j0 + 128];
    const float bias_o = BL[j0 + 192];
    float c4[4] = {0.f, 0.f, 0.f, 0.f};

    for (int i = tid; i < 2 * 2 * 4 * 16 * 8; i += 256)
        ((unsigned short*)hfrag)[i] = 0;
    // (first chunk's staging barrier also covers hfrag zero-init)

    for (int chunk = 0; chunk < 9; ++chunk) {
        const int t0 = chunk * 8;
        // ---- stage x[n0..n0+16][0..C][t0..t0+8] -> xbuf hi+lo (A-frag order)
        for (int i = tid; i < (16 << cshift); i += 256) {
            int n = i >> cshift, c = i & (Cpad - 1);
            float v[8];
            if (c < C) {
                size_t off = ((size_t)(n0 + n) * C + c) * 72 + t0;
                if (isf) {
                    const float* p = (const float*)x + off;   // 32B-aligned
                    f32x4 u0 = *(const f32x4*)p;
                    f32x4 u1 = *(const f32x4*)(p + 4);
                    v[0] = u0[0]; v[1] = u0[1]; v[2] = u0[2]; v[3] = u0[3];
                    v[4] = u1[0]; v[5] = u1[1]; v[6] = u1[2]; v[7] = u1[3];
                } else {
                    const unsigned short* p = (const unsigned short*)x + off;
#pragma unroll
                    for (int j = 0; j < 8; ++j) v[j] = b2f(p[j]);
                }
            } else {
#pragma unroll
                for (int j = 0; j < 8; ++j) v[j] = 0.f;
            }
#pragma unroll
            for (int tt = 0; tt < 8; ++tt) {
                unsigned short hi = f2b(v[tt]);
                xbuf[0][tt][c >> 3][n][c & 7] = hi;
                xbuf[1][tt][c >> 3][n][c & 7] = f2b(v[tt] - b2f(hi));
            }
        }
        __syncthreads();

        for (int tt = 0; tt < 8; ++tt) {
            const int t = t0 + tt;
            // ---- phase 1: gates = x_t @ Wih^T + h @ Whh^T (3-term hi/lo) ---
            f32x4 acc[4] = {{0,0,0,0},{0,0,0,0},{0,0,0,0},{0,0,0,0}};
            {
                short8 axh = *(const short8*)&xbuf[0][tt][quad][m16][0];
                short8 axl = *(const short8*)&xbuf[1][tt][quad][m16][0];
#pragma unroll
                for (int nt = 0; nt < 4; ++nt) {
                    acc[nt] = MFMA(axh, BxH0[nt], acc[nt]);
                    acc[nt] = MFMA(axl, BxH0[nt], acc[nt]);
                    acc[nt] = MFMA(axh, BxL0[nt], acc[nt]);
                }
            }
            if (isw) {
                short8 axh = *(const short8*)&xbuf[0][tt][4 + quad][m16][0];
                short8 axl = *(const short8*)&xbuf[1][tt][4 + quad][m16][0];
#pragma unroll
                for (int nt = 0; nt < 4; ++nt) {
                    acc[nt] = MFMA(axh, BxH1[nt], acc[nt]);
                    acc[nt] = MFMA(axl, BxH1[nt], acc[nt]);
                    acc[nt] = MFMA(axh, BxL1[nt], acc[nt]);
                }
            }
#pragma unroll
            for (int kt = 0; kt < 2; ++kt) {
                short8 ahi = *(const short8*)&hfrag[0][kt][quad][m16][0];
                short8 alo = *(const short8*)&hfrag[1][kt][quad][m16][0];
#pragma unroll
                for (int nt = 0; nt < 4; ++nt) {
                    acc[nt] = MFMA(ahi, BhH[kt][nt], acc[nt]);
                    acc[nt] = MFMA(alo, BhH[kt][nt], acc[nt]);
                    acc[nt] = MFMA(ahi, BhL[kt][nt], acc[nt]);
                }
            }
            // C/D: col = lane&15 (gate-in-tile), row = quad*4 + reg (batch)
#pragma unroll
            for (int nt = 0; nt < 4; ++nt) {
                int g = wave * 64 + nt * 16 + m16;
                *(f32x4*)&gates[g][quad * 4] = acc[nt];
            }
            __syncthreads();

            // ---- phase 2: cell update (rows nlo..nlo+3, unit j0) ----
            f32x4 gi = *(f32x4*)&gates[j0][nlo];
            f32x4 gf = *(f32x4*)&gates[j0 + 64][nlo];
            f32x4 gg = *(f32x4*)&gates[j0 + 128][nlo];
            f32x4 go = *(f32x4*)&gates[j0 + 192][nlo];
#pragma unroll
            for (int e = 0; e < 4; ++e) {
                float iv = sigmoidf_(gi[e] + bias_i);
                float fv = sigmoidf_(gf[e] + bias_f);
                float gv = tanhf_(gg[e] + bias_g);
                float ov = sigmoidf_(go[e] + bias_o);
                float c  = fv * c4[e] + iv * gv;
                c4[e]    = c;
                float h  = ov * tanhf_(c);
                unsigned short hi = f2b(h);
                unsigned short lo = f2b(h - b2f(hi));
                int m = nlo + e;
                hfrag[0][j0 >> 5][(j0 >> 3) & 3][m][j0 & 7] = hi;
                hfrag[1][j0 >> 5][(j0 >> 3) & 3][m][j0 & 7] = lo;
                if (t == 71) {
                    featH[(size_t)(n0 + m) * 128 + featOff + j0] = hi;
                    featL[(size_t)(n0 + m) * 128 + featOff + j0] = lo;
                }
            }
            __syncthreads();
        }
    }
}

// ---------------------------------------------------------------------------
// Kernel 3: MLP heads on feat (hi+lo bf16). Block = 4 waves, wave owns 16
// rows; inter-layer relayout through per-wave LDS A-frag buffer.
// Output dtype follows input dtype: fp32 if isf else bf16. [N][2][48].
// ---------------------------------------------------------------------------
__global__ __launch_bounds__(256) void heads_kernel(
    const unsigned short* __restrict__ ws, void* __restrict__ out)
{
    __shared__ unsigned short afrag[4][4][4][16][8];  // [wave][ktile][quad][m][j]
    const int tid  = threadIdx.x;
    const int wave = tid >> 6, lane = tid & 63;
    const int quad = lane >> 4, m16 = lane & 15;
    const int r0   = blockIdx.x * 64 + wave * 16;
    const int isf  = ((const int*)ws)[0];

    const unsigned short* HW    = ws + OFF_HW;
    const float*          BB    = (const float*)(ws + OFF_BIASH);
    const unsigned short* featH = ws + OFF_FEAT;
    const unsigned short* featL = featH + 8192 * 128;

    short8 fh[4], fl[4];
#pragma unroll
    for (int kt = 0; kt < 4; ++kt) {
        size_t o = (size_t)(r0 + m16) * 128 + kt * 32 + quad * 8;
        fh[kt] = *(const short8*)&featH[o];
        fl[kt] = *(const short8*)&featL[o];
    }

    for (int head = 0; head < 2; ++head) {
        const unsigned short* W1 = HW + (head ? 21504 : 0);
        const unsigned short* W2 = W1 + 12288;
        const unsigned short* W3 = W2 + 6144;
        const float* b1 = BB + head * 208;
        const float* b2 = b1 + 96;
        const float* b3 = b2 + 64;

        // L1: K=128, O=96, relu
        f32x4 a1[6] = {{0,0,0,0},{0,0,0,0},{0,0,0,0},{0,0,0,0},{0,0,0,0},{0,0,0,0}};
#pragma unroll
        for (int kt = 0; kt < 4; ++kt)
#pragma unroll
            for (int nt = 0; nt < 6; ++nt) {
                short8 bw = *(const short8*)
                    &W1[(nt * 16 + m16) * 128 + kt * 32 + quad * 8];
                a1[nt] = MFMA(fh[kt], bw, a1[nt]);
                a1[nt] = MFMA(fl[kt], bw, a1[nt]);
            }
#pragma unroll
        for (int nt = 0; nt < 6; ++nt) {
            int u = nt * 16 + m16;
            float bv = b1[u];
#pragma unroll
            for (int r = 0; r < 4; ++r) {
                float v = a1[nt][r] + bv;
                v = v > 0.f ? v : 0.f;
                afrag[wave][u >> 5][(u >> 3) & 3][quad * 4 + r][u & 7] = f2b(v);
            }
        }
        __syncthreads();

        // L2: K=96, O=64, relu
        f32x4 a2[4] = {{0,0,0,0},{0,0,0,0},{0,0,0,0},{0,0,0,0}};
#pragma unroll
        for (int kt = 0; kt < 3; ++kt) {
            short8 a = *(const short8*)&afrag[wave][kt][quad][m16][0];
#pragma unroll
            for (int nt = 0; nt < 4; ++nt) {
                short8 bw = *(const short8*)
                    &W2[(nt * 16 + m16) * 96 + kt * 32 + quad * 8];
                a2[nt] = MFMA(a, bw, a2[nt]);
            }
        }
        __syncthreads();
#pragma unroll
        for (int nt = 0; nt < 4; ++nt) {
            int u = nt * 16 + m16;
            float bv = b2[u];
#pragma unroll
            for (int r = 0; r < 4; ++r) {
                float v = a2[nt][r] + bv;
                v = v > 0.f ? v : 0.f;
                afrag[wave][u >> 5][(u >> 3) & 3][quad * 4 + r][u & 7] = f2b(v);
            }
        }
        __syncthreads();

        // L3: K=64, O=48, no relu -> out[n][head][u], dtype per isf
        f32x4 a3[3] = {{0,0,0,0},{0,0,0,0},{0,0,0,0}};
#pragma unroll
        for (int kt = 0; kt < 2; ++kt) {
            short8 a = *(const short8*)&afrag[wave][kt][quad][m16][0];
#pragma unroll
            for (int nt = 0; nt < 3; ++nt) {
                short8 bw = *(const short8*)
                    &W3[(nt * 16 + m16) * 64 + kt * 32 + quad * 8];
                a3[nt] = MFMA(a, bw, a3[nt]);
            }
        }
#pragma unroll
        for (int nt = 0; nt < 3; ++nt) {
            int u = nt * 16 + m16;
            float bv = b3[u];
#pragma unroll
            for (int r = 0; r < 4; ++r) {
                int row = quad * 4 + r;
                size_t idx = (size_t)(r0 + row) * 96 + head * 48 + u;
                float v = a3[nt][r] + bv;
                if (isf) ((float*)out)[idx] = v;
                else     ((unsigned short*)out)[idx] = f2b(v);
            }
        }
        __syncthreads();
    }
}

// ---------------------------------------------------------------------------
extern "C" void kernel_launch(void* const* d_in, const int* in_sizes, int n_in,
                              void* d_out, int out_size, void* d_ws, size_t ws_size,
                              hipStream_t stream)
{
    unsigned short* ws = (unsigned short*)d_ws;

    detect_kernel<<<1, 256, 0, stream>>>((const unsigned short*)d_in[0], (int*)d_ws);
    prep_kernel<<<64, 256, 0, stream>>>(
        d_in[2], d_in[3], d_in[4], d_in[5],
        d_in[6], d_in[7], d_in[8], d_in[9],
        d_in[10], d_in[11], d_in[12], d_in[13], d_in[14], d_in[15],
        d_in[16], d_in[17], d_in[18], d_in[19], d_in[20], d_in[21],
        ws);
    lstm_kernel<<<1024, 256, 0, stream>>>(d_in[0], d_in[1], ws);
    heads_kernel<<<128, 256, 0, stream>>>(ws, d_out);
}

// Round 2
// 532.097 us; speedup vs baseline: 1.0187x; 1.0187x over previous
//
#include <hip/hip_runtime.h>

typedef __attribute__((ext_vector_type(8))) short short8;
typedef __attribute__((ext_vector_type(4))) float f32x4;

// ---- workspace layout (uint16 element offsets from ws base) ----
// LSTM weights stored as hi-plane then lo-plane (hi+lo bf16 ~= fp32).
#define OFF_BXO   64                        // obs Wih B-frags hi[8192]+lo[8192]
#define OFF_BHO   (OFF_BXO + 16384)         // obs Whh B-frags hi[16384]+lo[16384]
#define OFF_BXW   (OFF_BHO + 32768)         // wrf Wih B-frags hi[16384]+lo[16384]
#define OFF_BHW   (OFF_BXW + 32768)         // wrf Whh B-frags hi[16384]+lo[16384]
#define OFF_HW    (OFF_BHW + 32768)         // head weights bf16 (single)
#define OFF_BIASL (OFF_HW + 43008)          // fp32: lstm bias (bih+bhh) [2][256]
#define OFF_BIASH (OFF_BIASL + 1024)        // fp32: head biases [2][208]
#define OFF_FEAT  (OFF_BIASH + 832)         // feat hi [8192][128] + lo plane
// total ~2.3M uint16 = ~4.6 MB of ws

__device__ __forceinline__ float b2f(unsigned short u) {
    return __uint_as_float(((unsigned)u) << 16);
}
__device__ __forceinline__ unsigned short f2b(float f) {
    unsigned u = __float_as_uint(f);
    u += 0x7FFFu + ((u >> 16) & 1u);   // RNE
    return (unsigned short)(u >> 16);
}
__device__ __forceinline__ float ldin(const void* p, int idx, int isf) {
    return isf ? ((const float*)p)[idx] : b2f(((const unsigned short*)p)[idx]);
}
__device__ __forceinline__ float sigmoidf_(float x) {
    return __builtin_amdgcn_rcpf(1.0f + __expf(-x));
}
__device__ __forceinline__ float tanhf_(float x) {
    return 2.0f * __builtin_amdgcn_rcpf(1.0f + __expf(-2.0f * x)) - 1.0f;
}
__device__ __forceinline__ f32x4 MFMA(short8 a, short8 b, f32x4 c) {
    return __builtin_amdgcn_mfma_f32_16x16x32_bf16(a, b, c, 0, 0, 0);
}

// ---------------------------------------------------------------------------
// Kernel 0: dtype detector. Little-endian fp32: uint16[2i] is the LOW mantissa
// half (~uniform bits, P(bf16-exponent-field >= 192) = 25%). Genuine bf16
// N(0,1) data never has exponent >= 192. flag=1 means fp32.
// ---------------------------------------------------------------------------
__global__ __launch_bounds__(256) void detect_kernel(
    const unsigned short* __restrict__ X, int* __restrict__ flag)
{
    __shared__ int cnt[256];
    int c = 0;
    for (int i = threadIdx.x; i < 2048; i += 256) {
        unsigned short u = X[2 * i];   // EVEN half-word
        c += (((u >> 7) & 0xFF) >= 192);
    }
    cnt[threadIdx.x] = c;
    __syncthreads();
    if (threadIdx.x == 0) {
        int s = 0;
        for (int i = 0; i < 256; ++i) s += cnt[i];
        *flag = (s > 64) ? 1 : 0;
    }
}

// ---------------------------------------------------------------------------
// Kernel 1: weight prep. LSTM weights -> hi+lo bf16 pairs in MFMA B-fragment
// order; head weights -> single bf16; biases pre-summed in fp32.
// ---------------------------------------------------------------------------
__global__ __launch_bounds__(256) void prep_kernel(
    const void* oWih, const void* oWhh, const void* obih, const void* obhh,
    const void* wWih, const void* wWhh, const void* wbih, const void* wbhh,
    const void* fW1, const void* fb1, const void* fW2, const void* fb2,
    const void* fW3, const void* fb3,
    const void* oW1, const void* ob1, const void* oW2, const void* ob2,
    const void* oW3, const void* ob3,
    unsigned short* __restrict__ ws)
{
    const int isf = ((const int*)ws)[0];
    const int gid = blockIdx.x * 256 + threadIdx.x;
    const int gsz = gridDim.x * 256;

    unsigned short* BXO = ws + OFF_BXO;
    unsigned short* BHO = ws + OFF_BHO;
    unsigned short* BXW = ws + OFF_BXW;
    unsigned short* BHW = ws + OFF_BHW;
    unsigned short* HW  = ws + OFF_HW;

    // obs Wih: i = wave*2048 + nt*512 + lane*8 + j
    for (int i = gid; i < 8192; i += gsz) {
        int j = i & 7, lane = (i >> 3) & 63, nt = (i >> 9) & 3, wave = i >> 11;
        int g = wave * 64 + nt * 16 + (lane & 15);
        int k = ((lane >> 4) << 3) + j;
        float w = ldin(oWih, g * 32 + k, isf);
        unsigned short hi = f2b(w);
        BXO[i] = hi; BXO[8192 + i] = f2b(w - b2f(hi));
    }
    // obs Whh: i = wave*4096 + kt*2048 + nt*512 + lane*8 + j
    for (int i = gid; i < 16384; i += gsz) {
        int j = i & 7, lane = (i >> 3) & 63, nt = (i >> 9) & 3;
        int kt = (i >> 11) & 1, wave = i >> 12;
        int g = wave * 64 + nt * 16 + (lane & 15);
        int k = kt * 32 + ((lane >> 4) << 3) + j;
        float w = ldin(oWhh, g * 64 + k, isf);
        unsigned short hi = f2b(w);
        BHO[i] = hi; BHO[16384 + i] = f2b(w - b2f(hi));
    }
    // wrf Wih: i = kt2*8192 + wave*2048 + nt*512 + lane*8 + j (zero-pad k>=56)
    for (int i = gid; i < 16384; i += gsz) {
        int j = i & 7, lane = (i >> 3) & 63, nt = (i >> 9) & 3;
        int wave = (i >> 11) & 3, kt2 = i >> 13;
        int g = wave * 64 + nt * 16 + (lane & 15);
        int k = kt2 * 32 + ((lane >> 4) << 3) + j;
        float w = (k < 56) ? ldin(wWih, g * 56 + k, isf) : 0.f;
        unsigned short hi = f2b(w);
        BXW[i] = hi; BXW[16384 + i] = f2b(w - b2f(hi));
    }
    // wrf Whh
    for (int i = gid; i < 16384; i += gsz) {
        int j = i & 7, lane = (i >> 3) & 63, nt = (i >> 9) & 3;
        int kt = (i >> 11) & 1, wave = i >> 12;
        int g = wave * 64 + nt * 16 + (lane & 15);
        int k = kt * 32 + ((lane >> 4) << 3) + j;
        float w = ldin(wWhh, g * 64 + k, isf);
        unsigned short hi = f2b(w);
        BHW[i] = hi; BHW[16384 + i] = f2b(w - b2f(hi));
    }
    // head weights, plain row-major bf16
    for (int i = gid; i < 12288; i += gsz) HW[i]         = f2b(ldin(fW1, i, isf));
    for (int i = gid; i < 6144;  i += gsz) HW[12288 + i] = f2b(ldin(fW2, i, isf));
    for (int i = gid; i < 3072;  i += gsz) HW[18432 + i] = f2b(ldin(fW3, i, isf));
    for (int i = gid; i < 12288; i += gsz) HW[21504 + i] = f2b(ldin(oW1, i, isf));
    for (int i = gid; i < 6144;  i += gsz) HW[33792 + i] = f2b(ldin(oW2, i, isf));
    for (int i = gid; i < 3072;  i += gsz) HW[39936 + i] = f2b(ldin(oW3, i, isf));
    // lstm biases (bih+bhh), fp32
    float* BL = (float*)(ws + OFF_BIASL);
    for (int i = gid; i < 256; i += gsz) BL[i]       = ldin(obih, i, isf) + ldin(obhh, i, isf);
    for (int i = gid; i < 256; i += gsz) BL[256 + i] = ldin(wbih, i, isf) + ldin(wbhh, i, isf);
    // head biases, fp32: [fsp b1(96) b2(64) b3(48)][o3 ...]
    float* BB = (float*)(ws + OFF_BIASH);
    for (int i = gid; i < 96; i += gsz) BB[i]       = ldin(fb1, i, isf);
    for (int i = gid; i < 64; i += gsz) BB[96 + i]  = ldin(fb2, i, isf);
    for (int i = gid; i < 48; i += gsz) BB[160 + i] = ldin(fb3, i, isf);
    for (int i = gid; i < 96; i += gsz) BB[208 + i] = ldin(ob1, i, isf);
    for (int i = gid; i < 64; i += gsz) BB[304 + i] = ldin(ob2, i, isf);
    for (int i = gid; i < 48; i += gsz) BB[368 + i] = ldin(ob3, i, isf);
}

// ---------------------------------------------------------------------------
// Kernel 2: persistent-per-block LSTM, hi+lo bf16 everywhere (x, Wih, Whh, h)
// with 3-term MFMA products -> matmuls are ~fp32-exact. Block = 4 waves owns
// 16 batch rows (blocks 0..511 obs, 512..1023 wrf), 72 steps in 18 chunks of 4.
// LDS: 16 KB xbuf + 16 KB gates + 4 KB hfrag = 36 KB -> 4 blocks/CU (was 3,
// which forced TWO sequential dispatch rounds for the 1024-block grid).
// All LDS layouts XOR-swizzled so writes hit all 32 banks (was 8/16-way).
// ---------------------------------------------------------------------------
#define TCH 4
__global__ __launch_bounds__(256) void lstm_kernel(
    const void* __restrict__ Xo, const void* __restrict__ Xw,
    unsigned short* __restrict__ ws)
{
    __shared__ unsigned short xbuf[2][TCH][8][16][8]; // [hi/lo][t][ktile][physrow][j]
    __shared__ float gates[256][16];                  // [gate][swizzled n-group]
    __shared__ unsigned short hfrag[2][2][4][16][8];  // [hi/lo][kt][quad][physrow][j]

    const int tid  = threadIdx.x;
    const int wave = tid >> 6, lane = tid & 63;
    const int quad = lane >> 4, m16 = lane & 15;
    const bool isw = blockIdx.x >= 512;
    const int blk  = isw ? (int)blockIdx.x - 512 : (int)blockIdx.x;
    const int n0   = blk * 16;
    const int isf  = ((const int*)ws)[0];

    const void* x = isw ? Xw : Xo;
    const unsigned short* BX = ws + (isw ? OFF_BXW : OFF_BXO);
    const unsigned short* BH = ws + (isw ? OFF_BHW : OFF_BHO);
    const float* BL = (const float*)(ws + OFF_BIASL) + (isw ? 256 : 0);
    unsigned short* featH = ws + OFF_FEAT;
    unsigned short* featL = featH + 8192 * 128;
    const int C       = isw ? 56 : 32;
    const int Cpad    = isw ? 64 : 32;
    const int cshift  = isw ? 6 : 5;
    const int xloOff  = isw ? 16384 : 8192;   // lo-plane offset within BX
    const int featOff = isw ? 64 : 0;

    // --- B fragments (constant over all 72 steps) ---
    short8 BhH[2][4], BhL[2][4];
#pragma unroll
    for (int kt = 0; kt < 2; ++kt)
#pragma unroll
        for (int nt = 0; nt < 4; ++nt) {
            int idx = ((wave * 2 + kt) * 4 + nt) * 512 + lane * 8;
            BhH[kt][nt] = *(const short8*)&BH[idx];
            BhL[kt][nt] = *(const short8*)&BH[16384 + idx];
        }
    short8 BxH0[4], BxL0[4], BxH1[4], BxL1[4];
#pragma unroll
    for (int nt = 0; nt < 4; ++nt) {
        int idx = (wave * 4 + nt) * 512 + lane * 8;
        BxH0[nt] = *(const short8*)&BX[idx];
        BxL0[nt] = *(const short8*)&BX[xloOff + idx];
    }
    if (isw) {
#pragma unroll
        for (int nt = 0; nt < 4; ++nt) {
            int idx = (wave * 4 + nt) * 512 + lane * 8;
            BxH1[nt] = *(const short8*)&BX[8192 + idx];
            BxL1[nt] = *(const short8*)&BX[xloOff + 8192 + idx];
        }
    }

    // update phase: thread owns hidden unit j0 for 4 batch rows
    const int j0  = tid >> 2;
    const int nlo = (tid & 3) * 4;
    const float bias_i = BL[j0];
    const float bias_f = BL[j0 + 64];
    const float bias_g = BL[j0 + 128];
    const float bias_o = BL[j0 + 192];
    float c4[4] = {0.f, 0.f, 0.f, 0.f};

    // gates read column group (same XOR as write side; row+64k keeps it)
    const int colr = (tid & 3) ^ ((j0 >> 1) & 3);
    // hfrag write: chunk = j0>>3 (= kt*4+quad of the reader)
    const int hchunkbit = ((j0 >> 3) & 1) << 2;
    // hfrag read physical row for this lane
    const int prr = ((((m16 & 3) << 2) | (m16 >> 2)) ^ ((quad & 1) << 2));

    for (int i = tid; i < 2 * 2 * 4 * 16 * 8; i += 256)
        ((unsigned short*)hfrag)[i] = 0;
    // (first chunk's staging barrier also covers hfrag zero-init)

    for (int chunk = 0; chunk < 18; ++chunk) {
        const int t0 = chunk * TCH;
        // ---- stage x[n0..n0+16][0..C][t0..t0+4] -> xbuf hi+lo (A-frag order)
        // physrow = n ^ ktile spreads writes across banks (wrf was 16-way).
        for (int i = tid; i < (16 << cshift); i += 256) {
            int n = i >> cshift, c = i & (Cpad - 1);
            float v[TCH];
            if (c < C) {
                size_t off = ((size_t)(n0 + n) * C + c) * 72 + t0;
                if (isf) {
                    f32x4 u0 = *(const f32x4*)((const float*)x + off); // 16B-aligned
                    v[0] = u0[0]; v[1] = u0[1]; v[2] = u0[2]; v[3] = u0[3];
                } else {
                    const unsigned short* p = (const unsigned short*)x + off;
#pragma unroll
                    for (int j = 0; j < TCH; ++j) v[j] = b2f(p[j]);
                }
            } else {
#pragma unroll
                for (int j = 0; j < TCH; ++j) v[j] = 0.f;
            }
            int kt = c >> 3;
            int pr = n ^ kt;               // physrow swizzle
#pragma unroll
            for (int tt = 0; tt < TCH; ++tt) {
                unsigned short hi = f2b(v[tt]);
                xbuf[0][tt][kt][pr][c & 7] = hi;
                xbuf[1][tt][kt][pr][c & 7] = f2b(v[tt] - b2f(hi));
            }
        }
        __syncthreads();

        for (int tt = 0; tt < TCH; ++tt) {
            const int t = t0 + tt;
            // ---- phase 1: gates = x_t @ Wih^T + h @ Whh^T (3-term hi/lo) ---
            f32x4 acc[4] = {{0,0,0,0},{0,0,0,0},{0,0,0,0},{0,0,0,0}};
            {
                short8 axh = *(const short8*)&xbuf[0][tt][quad][m16 ^ quad][0];
                short8 axl = *(const short8*)&xbuf[1][tt][quad][m16 ^ quad][0];
#pragma unroll
                for (int nt = 0; nt < 4; ++nt) {
                    acc[nt] = MFMA(axh, BxH0[nt], acc[nt]);
                    acc[nt] = MFMA(axl, BxH0[nt], acc[nt]);
                    acc[nt] = MFMA(axh, BxL0[nt], acc[nt]);
                }
            }
            if (isw) {
                short8 axh = *(const short8*)&xbuf[0][tt][4 + quad][m16 ^ (4 + quad)][0];
                short8 axl = *(const short8*)&xbuf[1][tt][4 + quad][m16 ^ (4 + quad)][0];
#pragma unroll
                for (int nt = 0; nt < 4; ++nt) {
                    acc[nt] = MFMA(axh, BxH1[nt], acc[nt]);
                    acc[nt] = MFMA(axl, BxH1[nt], acc[nt]);
                    acc[nt] = MFMA(axh, BxL1[nt], acc[nt]);
                }
            }
#pragma unroll
            for (int kt = 0; kt < 2; ++kt) {
                short8 ahi = *(const short8*)&hfrag[0][kt][quad][prr][0];
                short8 alo = *(const short8*)&hfrag[1][kt][quad][prr][0];
#pragma unroll
                for (int nt = 0; nt < 4; ++nt) {
                    acc[nt] = MFMA(ahi, BhH[kt][nt], acc[nt]);
                    acc[nt] = MFMA(alo, BhH[kt][nt], acc[nt]);
                    acc[nt] = MFMA(ahi, BhL[kt][nt], acc[nt]);
                }
            }
            // C/D: col = lane&15 (gate-in-tile), row = quad*4 + reg (batch)
            // column-group XOR -> b128 writes span all 32 banks (was 8-way)
            {
                int colw = quad ^ ((m16 >> 1) & 3);
#pragma unroll
                for (int nt = 0; nt < 4; ++nt) {
                    int g = wave * 64 + nt * 16 + m16;
                    *(f32x4*)&gates[g][colw * 4] = acc[nt];
                }
            }
            __syncthreads();

            // ---- phase 2: cell update (rows nlo..nlo+3, unit j0) ----
            f32x4 gi = *(f32x4*)&gates[j0][colr * 4];
            f32x4 gf = *(f32x4*)&gates[j0 + 64][colr * 4];
            f32x4 gg = *(f32x4*)&gates[j0 + 128][colr * 4];
            f32x4 go = *(f32x4*)&gates[j0 + 192][colr * 4];
#pragma unroll
            for (int e = 0; e < 4; ++e) {
                float iv = sigmoidf_(gi[e] + bias_i);
                float fv = sigmoidf_(gf[e] + bias_f);
                float gv = tanhf_(gg[e] + bias_g);
                float ov = sigmoidf_(go[e] + bias_o);
                float c  = fv * c4[e] + iv * gv;
                c4[e]    = c;
                float h  = ov * tanhf_(c);
                unsigned short hi = f2b(h);
                unsigned short lo = f2b(h - b2f(hi));
                int m = nlo + e;
                // physrow: both msel bits + chunk bit into bank bits
                int pr = (((m & 3) << 2) | (m >> 2)) ^ hchunkbit;
                hfrag[0][j0 >> 5][(j0 >> 3) & 3][pr][j0 & 7] = hi;
                hfrag[1][j0 >> 5][(j0 >> 3) & 3][pr][j0 & 7] = lo;
                if (t == 71) {
                    featH[(size_t)(n0 + m) * 128 + featOff + j0] = hi;
                    featL[(size_t)(n0 + m) * 128 + featOff + j0] = lo;
                }
            }
            __syncthreads();
        }
    }
}

// ---------------------------------------------------------------------------
// Kernel 3: MLP heads on feat (hi+lo bf16). Block = 4 waves, wave owns 16
// rows; inter-layer relayout through per-wave LDS A-frag buffer.
// Output dtype follows input dtype: fp32 if isf else bf16. [N][2][48].
// ---------------------------------------------------------------------------
__global__ __launch_bounds__(256) void heads_kernel(
    const unsigned short* __restrict__ ws, void* __restrict__ out)
{
    __shared__ unsigned short afrag[4][4][4][16][8];  // [wave][ktile][quad][m][j]
    const int tid  = threadIdx.x;
    const int wave = tid >> 6, lane = tid & 63;
    const int quad = lane >> 4, m16 = lane & 15;
    const int r0   = blockIdx.x * 64 + wave * 16;
    const int isf  = ((const int*)ws)[0];

    const unsigned short* HW    = ws + OFF_HW;
    const float*          BB    = (const float*)(ws + OFF_BIASH);
    const unsigned short* featH = ws + OFF_FEAT;
    const unsigned short* featL = featH + 8192 * 128;

    short8 fh[4], fl[4];
#pragma unroll
    for (int kt = 0; kt < 4; ++kt) {
        size_t o = (size_t)(r0 + m16) * 128 + kt * 32 + quad * 8;
        fh[kt] = *(const short8*)&featH[o];
        fl[kt] = *(const short8*)&featL[o];
    }

    for (int head = 0; head < 2; ++head) {
        const unsigned short* W1 = HW + (head ? 21504 : 0);
        const unsigned short* W2 = W1 + 12288;
        const unsigned short* W3 = W2 + 6144;
        const float* b1 = BB + head * 208;
        const float* b2 = b1 + 96;
        const float* b3 = b2 + 64;

        // L1: K=128, O=96, relu
        f32x4 a1[6] = {{0,0,0,0},{0,0,0,0},{0,0,0,0},{0,0,0,0},{0,0,0,0},{0,0,0,0}};
#pragma unroll
        for (int kt = 0; kt < 4; ++kt)
#pragma unroll
            for (int nt = 0; nt < 6; ++nt) {
                short8 bw = *(const short8*)
                    &W1[(nt * 16 + m16) * 128 + kt * 32 + quad * 8];
                a1[nt] = MFMA(fh[kt], bw, a1[nt]);
                a1[nt] = MFMA(fl[kt], bw, a1[nt]);
            }
#pragma unroll
        for (int nt = 0; nt < 6; ++nt) {
            int u = nt * 16 + m16;
            float bv = b1[u];
#pragma unroll
            for (int r = 0; r < 4; ++r) {
                float v = a1[nt][r] + bv;
                v = v > 0.f ? v : 0.f;
                afrag[wave][u >> 5][(u >> 3) & 3][quad * 4 + r][u & 7] = f2b(v);
            }
        }
        __syncthreads();

        // L2: K=96, O=64, relu
        f32x4 a2[4] = {{0,0,0,0},{0,0,0,0},{0,0,0,0},{0,0,0,0}};
#pragma unroll
        for (int kt = 0; kt < 3; ++kt) {
            short8 a = *(const short8*)&afrag[wave][kt][quad][m16][0];
#pragma unroll
            for (int nt = 0; nt < 4; ++nt) {
                short8 bw = *(const short8*)
                    &W2[(nt * 16 + m16) * 96 + kt * 32 + quad * 8];
                a2[nt] = MFMA(a, bw, a2[nt]);
            }
        }
        __syncthreads();
#pragma unroll
        for (int nt = 0; nt < 4; ++nt) {
            int u = nt * 16 + m16;
            float bv = b2[u];
#pragma unroll
            for (int r = 0; r < 4; ++r) {
                float v = a2[nt][r] + bv;
                v = v > 0.f ? v : 0.f;
                afrag[wave][u >> 5][(u >> 3) & 3][quad * 4 + r][u & 7] = f2b(v);
            }
        }
        __syncthreads();

        // L3: K=64, O=48, no relu -> out[n][head][u], dtype per isf
        f32x4 a3[3] = {{0,0,0,0},{0,0,0,0},{0,0,0,0}};
#pragma unroll
        for (int kt = 0; kt < 2; ++kt) {
            short8 a = *(const short8*)&afrag[wave][kt][quad][m16][0];
#pragma unroll
            for (int nt = 0; nt < 3; ++nt) {
                short8 bw = *(const short8*)
                    &W3[(nt * 16 + m16) * 64 + kt * 32 + quad * 8];
                a3[nt] = MFMA(a, bw, a3[nt]);
            }
        }
#pragma unroll
        for (int nt = 0; nt < 3; ++nt) {
            int u = nt * 16 + m16;
            float bv = b3[u];
#pragma unroll
            for (int r = 0; r < 4; ++r) {
                int row = quad * 4 + r;
                size_t idx = (size_t)(r0 + row) * 96 + head * 48 + u;
                float v = a3[nt][r] + bv;
                if (isf) ((float*)out)[idx] = v;
                else     ((unsigned short*)out)[idx] = f2b(v);
            }
        }
        __syncthreads();
    }
}

// ---------------------------------------------------------------------------
extern "C" void kernel_launch(void* const* d_in, const int* in_sizes, int n_in,
                              void* d_out, int out_size, void* d_ws, size_t ws_size,
                              hipStream_t stream)
{
    unsigned short* ws = (unsigned short*)d_ws;

    detect_kernel<<<1, 256, 0, stream>>>((const unsigned short*)d_in[0], (int*)d_ws);
    prep_kernel<<<64, 256, 0, stream>>>(
        d_in[2], d_in[3], d_in[4], d_in[5],
        d_in[6], d_in[7], d_in[8], d_in[9],
        d_in[10], d_in[11], d_in[12], d_in[13], d_in[14], d_in[15],
        d_in[16], d_in[17], d_in[18], d_in[19], d_in[20], d_in[21],
        ws);
    lstm_kernel<<<1024, 256, 0, stream>>>(d_in[0], d_in[1], ws);
    heads_kernel<<<128, 256, 0, stream>>>(ws, d_out);
}

// Round 3
// 510.807 us; speedup vs baseline: 1.0611x; 1.0417x over previous
//
#include <hip/hip_runtime.h>

typedef __attribute__((ext_vector_type(8))) short short8;
typedef __attribute__((ext_vector_type(4))) float f32x4;

// ---- workspace layout (uint16 element offsets from ws base) ----
// LSTM weights stored as hi-plane then lo-plane (hi+lo bf16 ~= fp32).
// B-frag tile order: nt = GATE TYPE (i,f,g,o), wave = unit block of 16.
#define OFF_BXO   64                        // obs Wih B-frags hi[8192]+lo[8192]
#define OFF_BHO   (OFF_BXO + 16384)         // obs Whh B-frags hi[16384]+lo[16384]
#define OFF_BXW   (OFF_BHO + 32768)         // wrf Wih B-frags hi[16384]+lo[16384]
#define OFF_BHW   (OFF_BXW + 32768)         // wrf Whh B-frags hi[16384]+lo[16384]
#define OFF_HW    (OFF_BHW + 32768)         // head weights bf16 (single)
#define OFF_BIASL (OFF_HW + 43008)          // fp32: lstm bias (bih+bhh) [2][256]
#define OFF_BIASH (OFF_BIASL + 1024)        // fp32: head biases [2][208]
#define OFF_FEAT  (OFF_BIASH + 832)         // feat hi [8192][128] + lo plane
// total ~2.3M uint16 = ~4.6 MB of ws

__device__ __forceinline__ float b2f(unsigned short u) {
    return __uint_as_float(((unsigned)u) << 16);
}
__device__ __forceinline__ unsigned short f2b(float f) {
    unsigned u = __float_as_uint(f);
    u += 0x7FFFu + ((u >> 16) & 1u);   // RNE
    return (unsigned short)(u >> 16);
}
__device__ __forceinline__ float ldin(const void* p, int idx, int isf) {
    return isf ? ((const float*)p)[idx] : b2f(((const unsigned short*)p)[idx]);
}
__device__ __forceinline__ float sigmoidf_(float x) {
    return __builtin_amdgcn_rcpf(1.0f + __expf(-x));
}
__device__ __forceinline__ float tanhf_(float x) {
    return 2.0f * __builtin_amdgcn_rcpf(1.0f + __expf(-2.0f * x)) - 1.0f;
}
__device__ __forceinline__ f32x4 MFMA(short8 a, short8 b, f32x4 c) {
    return __builtin_amdgcn_mfma_f32_16x16x32_bf16(a, b, c, 0, 0, 0);
}

// ---------------------------------------------------------------------------
// Kernel 0: dtype detector. Little-endian fp32: uint16[2i] is the LOW mantissa
// half (~uniform bits, P(bf16-exponent-field >= 192) = 25%). Genuine bf16
// N(0,1) data never has exponent >= 192. flag=1 means fp32.
// ---------------------------------------------------------------------------
__global__ __launch_bounds__(256) void detect_kernel(
    const unsigned short* __restrict__ X, int* __restrict__ flag)
{
    __shared__ int cnt[256];
    int c = 0;
    for (int i = threadIdx.x; i < 2048; i += 256) {
        unsigned short u = X[2 * i];   // EVEN half-word
        c += (((u >> 7) & 0xFF) >= 192);
    }
    cnt[threadIdx.x] = c;
    __syncthreads();
    if (threadIdx.x == 0) {
        int s = 0;
        for (int i = 0; i < 256; ++i) s += cnt[i];
        *flag = (s > 64) ? 1 : 0;
    }
}

// ---------------------------------------------------------------------------
// Kernel 1: weight prep. LSTM weights -> hi+lo bf16 pairs in MFMA B-fragment
// order with nt = gate type (g = nt*64 + wave*16 + col) so the MFMA output
// holds all 4 gates of one unit in one lane; head weights -> single bf16;
// biases pre-summed in fp32.
// ---------------------------------------------------------------------------
__global__ __launch_bounds__(256) void prep_kernel(
    const void* oWih, const void* oWhh, const void* obih, const void* obhh,
    const void* wWih, const void* wWhh, const void* wbih, const void* wbhh,
    const void* fW1, const void* fb1, const void* fW2, const void* fb2,
    const void* fW3, const void* fb3,
    const void* oW1, const void* ob1, const void* oW2, const void* ob2,
    const void* oW3, const void* ob3,
    unsigned short* __restrict__ ws)
{
    const int isf = ((const int*)ws)[0];
    const int gid = blockIdx.x * 256 + threadIdx.x;
    const int gsz = gridDim.x * 256;

    unsigned short* BXO = ws + OFF_BXO;
    unsigned short* BHO = ws + OFF_BHO;
    unsigned short* BXW = ws + OFF_BXW;
    unsigned short* BHW = ws + OFF_BHW;
    unsigned short* HW  = ws + OFF_HW;

    // obs Wih: i = wave*2048 + nt*512 + lane*8 + j ; g = nt*64 + wave*16 + col
    for (int i = gid; i < 8192; i += gsz) {
        int j = i & 7, lane = (i >> 3) & 63, nt = (i >> 9) & 3, wave = i >> 11;
        int g = nt * 64 + wave * 16 + (lane & 15);
        int k = ((lane >> 4) << 3) + j;
        float w = ldin(oWih, g * 32 + k, isf);
        unsigned short hi = f2b(w);
        BXO[i] = hi; BXO[8192 + i] = f2b(w - b2f(hi));
    }
    // obs Whh: i = wave*4096 + kt*2048 + nt*512 + lane*8 + j
    for (int i = gid; i < 16384; i += gsz) {
        int j = i & 7, lane = (i >> 3) & 63, nt = (i >> 9) & 3;
        int kt = (i >> 11) & 1, wave = i >> 12;
        int g = nt * 64 + wave * 16 + (lane & 15);
        int k = kt * 32 + ((lane >> 4) << 3) + j;
        float w = ldin(oWhh, g * 64 + k, isf);
        unsigned short hi = f2b(w);
        BHO[i] = hi; BHO[16384 + i] = f2b(w - b2f(hi));
    }
    // wrf Wih: i = kt2*8192 + wave*2048 + nt*512 + lane*8 + j (zero-pad k>=56)
    for (int i = gid; i < 16384; i += gsz) {
        int j = i & 7, lane = (i >> 3) & 63, nt = (i >> 9) & 3;
        int wave = (i >> 11) & 3, kt2 = i >> 13;
        int g = nt * 64 + wave * 16 + (lane & 15);
        int k = kt2 * 32 + ((lane >> 4) << 3) + j;
        float w = (k < 56) ? ldin(wWih, g * 56 + k, isf) : 0.f;
        unsigned short hi = f2b(w);
        BXW[i] = hi; BXW[16384 + i] = f2b(w - b2f(hi));
    }
    // wrf Whh
    for (int i = gid; i < 16384; i += gsz) {
        int j = i & 7, lane = (i >> 3) & 63, nt = (i >> 9) & 3;
        int kt = (i >> 11) & 1, wave = i >> 12;
        int g = nt * 64 + wave * 16 + (lane & 15);
        int k = kt * 32 + ((lane >> 4) << 3) + j;
        float w = ldin(wWhh, g * 64 + k, isf);
        unsigned short hi = f2b(w);
        BHW[i] = hi; BHW[16384 + i] = f2b(w - b2f(hi));
    }
    // head weights, plain row-major bf16
    for (int i = gid; i < 12288; i += gsz) HW[i]         = f2b(ldin(fW1, i, isf));
    for (int i = gid; i < 6144;  i += gsz) HW[12288 + i] = f2b(ldin(fW2, i, isf));
    for (int i = gid; i < 3072;  i += gsz) HW[18432 + i] = f2b(ldin(fW3, i, isf));
    for (int i = gid; i < 12288; i += gsz) HW[21504 + i] = f2b(ldin(oW1, i, isf));
    for (int i = gid; i < 6144;  i += gsz) HW[33792 + i] = f2b(ldin(oW2, i, isf));
    for (int i = gid; i < 3072;  i += gsz) HW[39936 + i] = f2b(ldin(oW3, i, isf));
    // lstm biases (bih+bhh), fp32
    float* BL = (float*)(ws + OFF_BIASL);
    for (int i = gid; i < 256; i += gsz) BL[i]       = ldin(obih, i, isf) + ldin(obhh, i, isf);
    for (int i = gid; i < 256; i += gsz) BL[256 + i] = ldin(wbih, i, isf) + ldin(wbhh, i, isf);
    // head biases, fp32: [fsp b1(96) b2(64) b3(48)][o3 ...]
    float* BB = (float*)(ws + OFF_BIASH);
    for (int i = gid; i < 96; i += gsz) BB[i]       = ldin(fb1, i, isf);
    for (int i = gid; i < 64; i += gsz) BB[96 + i]  = ldin(fb2, i, isf);
    for (int i = gid; i < 48; i += gsz) BB[160 + i] = ldin(fb3, i, isf);
    for (int i = gid; i < 96; i += gsz) BB[208 + i] = ldin(ob1, i, isf);
    for (int i = gid; i < 64; i += gsz) BB[304 + i] = ldin(ob2, i, isf);
    for (int i = gid; i < 48; i += gsz) BB[368 + i] = ldin(ob3, i, isf);
}

// ---------------------------------------------------------------------------
// Kernel 2: persistent-per-block LSTM. With nt = gate-type B-packing, the
// MFMA output acc[0..3] = (i,f,g,o) for ONE unit x 4 batch rows per lane ->
// the cell update is entirely in-register (no gates LDS buffer, ONE barrier
// per step instead of two). hfrag is parity double-buffered. LDS: 16 KB xbuf
// + 16 KB hfrag = 32 KB.
// ---------------------------------------------------------------------------
#define TCH 4
__global__ __launch_bounds__(256) void lstm_kernel(
    const void* __restrict__ Xo, const void* __restrict__ Xw,
    unsigned short* __restrict__ ws)
{
    __shared__ unsigned short xbuf[2][TCH][8][16][8];   // [hi/lo][t][ktile][physrow][j]
    __shared__ unsigned short hfrag[2][2][2][4][16][8]; // [par][hi/lo][kt][quadA][physrow][j]

    const int tid  = threadIdx.x;
    const int wave = tid >> 6, lane = tid & 63;
    const int quad = lane >> 4, m16 = lane & 15;
    const bool isw = blockIdx.x >= 512;
    const int blk  = isw ? (int)blockIdx.x - 512 : (int)blockIdx.x;
    const int n0   = blk * 16;
    const int isf  = ((const int*)ws)[0];

    const void* x = isw ? Xw : Xo;
    const unsigned short* BX = ws + (isw ? OFF_BXW : OFF_BXO);
    const unsigned short* BH = ws + (isw ? OFF_BHW : OFF_BHO);
    const float* BL = (const float*)(ws + OFF_BIASL) + (isw ? 256 : 0);
    unsigned short* featH = ws + OFF_FEAT;
    unsigned short* featL = featH + 8192 * 128;
    const int C       = isw ? 56 : 32;
    const int Cpad    = isw ? 64 : 32;
    const int cshift  = isw ? 6 : 5;
    const int xloOff  = isw ? 16384 : 8192;   // lo-plane offset within BX
    const int featOff = isw ? 64 : 0;

    // --- B fragments (constant over all 72 steps) ---
    short8 BhH[2][4], BhL[2][4];
#pragma unroll
    for (int kt = 0; kt < 2; ++kt)
#pragma unroll
        for (int nt = 0; nt < 4; ++nt) {
            int idx = ((wave * 2 + kt) * 4 + nt) * 512 + lane * 8;
            BhH[kt][nt] = *(const short8*)&BH[idx];
            BhL[kt][nt] = *(const short8*)&BH[16384 + idx];
        }
    short8 BxH0[4], BxL0[4], BxH1[4], BxL1[4];
#pragma unroll
    for (int nt = 0; nt < 4; ++nt) {
        int idx = (wave * 4 + nt) * 512 + lane * 8;
        BxH0[nt] = *(const short8*)&BX[idx];
        BxL0[nt] = *(const short8*)&BX[xloOff + idx];
    }
    if (isw) {
#pragma unroll
        for (int nt = 0; nt < 4; ++nt) {
            int idx = (wave * 4 + nt) * 512 + lane * 8;
            BxH1[nt] = *(const short8*)&BX[8192 + idx];
            BxL1[nt] = *(const short8*)&BX[xloOff + 8192 + idx];
        }
    }

    // this lane owns unit u for 4 batch rows (quad*4 + r)
    const int u = wave * 16 + m16;
    const float bias_i = BL[u];
    const float bias_f = BL[u + 64];
    const float bias_g = BL[u + 128];
    const float bias_o = BL[u + 192];
    float c4[4] = {0.f, 0.f, 0.f, 0.f};

    // hfrag write coords for unit u
    const int ktw = wave >> 1;
    const int qaw = ((wave & 1) << 1) | (m16 >> 3);
    const int jw  = m16 & 7;
    const int chunkbit = (m16 >> 3) << 2;   // (qaw&1)<<2
    // hfrag read physical row for this lane (row = m16, k-quad = quad)
    const int prr = ((((m16 & 3) << 2) | (m16 >> 2)) ^ ((quad & 1) << 2));

    for (int i = tid; i < 2 * 2 * 2 * 4 * 16 * 8; i += 256)
        ((unsigned short*)hfrag)[i] = 0;
    // (first chunk's staging barrier also covers hfrag zero-init)

    int par = 0;
    for (int chunk = 0; chunk < 18; ++chunk) {
        const int t0 = chunk * TCH;
        // ---- stage x[n0..n0+16][0..C][t0..t0+4] -> xbuf hi+lo (A-frag order)
        // physrow = n ^ ktile spreads writes across banks.
        for (int i = tid; i < (16 << cshift); i += 256) {
            int n = i >> cshift, c = i & (Cpad - 1);
            float v[TCH];
            if (c < C) {
                size_t off = ((size_t)(n0 + n) * C + c) * 72 + t0;
                if (isf) {
                    f32x4 u0 = *(const f32x4*)((const float*)x + off); // 16B-aligned
                    v[0] = u0[0]; v[1] = u0[1]; v[2] = u0[2]; v[3] = u0[3];
                } else {
                    const unsigned short* p = (const unsigned short*)x + off;
#pragma unroll
                    for (int j = 0; j < TCH; ++j) v[j] = b2f(p[j]);
                }
            } else {
#pragma unroll
                for (int j = 0; j < TCH; ++j) v[j] = 0.f;
            }
            int kt = c >> 3;
            int pr = n ^ kt;               // physrow swizzle
#pragma unroll
            for (int tt = 0; tt < TCH; ++tt) {
                unsigned short hi = f2b(v[tt]);
                xbuf[0][tt][kt][pr][c & 7] = hi;
                xbuf[1][tt][kt][pr][c & 7] = f2b(v[tt] - b2f(hi));
            }
        }
        __syncthreads();

        for (int tt = 0; tt < TCH; ++tt) {
            const int t = t0 + tt;
            // ---- MFMA: gates = x_t @ Wih^T + h @ Whh^T (3-term hi/lo) ----
            f32x4 acc[4] = {{0,0,0,0},{0,0,0,0},{0,0,0,0},{0,0,0,0}};
            {
                short8 axh = *(const short8*)&xbuf[0][tt][quad][m16 ^ quad][0];
                short8 axl = *(const short8*)&xbuf[1][tt][quad][m16 ^ quad][0];
#pragma unroll
                for (int nt = 0; nt < 4; ++nt) {
                    acc[nt] = MFMA(axh, BxH0[nt], acc[nt]);
                    acc[nt] = MFMA(axl, BxH0[nt], acc[nt]);
                    acc[nt] = MFMA(axh, BxL0[nt], acc[nt]);
                }
            }
            if (isw) {
                short8 axh = *(const short8*)&xbuf[0][tt][4 + quad][m16 ^ (4 + quad)][0];
                short8 axl = *(const short8*)&xbuf[1][tt][4 + quad][m16 ^ (4 + quad)][0];
#pragma unroll
                for (int nt = 0; nt < 4; ++nt) {
                    acc[nt] = MFMA(axh, BxH1[nt], acc[nt]);
                    acc[nt] = MFMA(axl, BxH1[nt], acc[nt]);
                    acc[nt] = MFMA(axh, BxL1[nt], acc[nt]);
                }
            }
#pragma unroll
            for (int kt = 0; kt < 2; ++kt) {
                short8 ahi = *(const short8*)&hfrag[par][0][kt][quad][prr][0];
                short8 alo = *(const short8*)&hfrag[par][1][kt][quad][prr][0];
#pragma unroll
                for (int nt = 0; nt < 4; ++nt) {
                    acc[nt] = MFMA(ahi, BhH[kt][nt], acc[nt]);
                    acc[nt] = MFMA(alo, BhH[kt][nt], acc[nt]);
                    acc[nt] = MFMA(ahi, BhL[kt][nt], acc[nt]);
                }
            }

            // ---- cell update, fully in-register: acc[0..3]=(i,f,g,o) for
            // unit u, rows quad*4+r ----
#pragma unroll
            for (int r = 0; r < 4; ++r) {
                float iv = sigmoidf_(acc[0][r] + bias_i);
                float fv = sigmoidf_(acc[1][r] + bias_f);
                float gv = tanhf_(acc[2][r] + bias_g);
                float ov = sigmoidf_(acc[3][r] + bias_o);
                float c  = fv * c4[r] + iv * gv;
                c4[r]    = c;
                float h  = ov * tanhf_(c);
                // truncated hi/lo split (pair-exact to ~2^-17; lo absorbs it)
                unsigned hu = __float_as_uint(h);
                unsigned short hi = (unsigned short)(hu >> 16);
                float hiv = __uint_as_float(hu & 0xFFFF0000u);
                unsigned short lo = (unsigned short)(__float_as_uint(h - hiv) >> 16);
                int pr = ((r << 2) | quad) ^ chunkbit;
                hfrag[par ^ 1][0][ktw][qaw][pr][jw] = hi;
                hfrag[par ^ 1][1][ktw][qaw][pr][jw] = lo;
                if (t == 71) {
                    int m = quad * 4 + r;
                    featH[(size_t)(n0 + m) * 128 + featOff + u] = hi;
                    featL[(size_t)(n0 + m) * 128 + featOff + u] = lo;
                }
            }
            __syncthreads();
            par ^= 1;
        }
    }
}

// ---------------------------------------------------------------------------
// Kernel 3: MLP heads on feat (hi+lo bf16). Block = 4 waves, wave owns 16
// rows; inter-layer relayout through per-wave LDS A-frag buffer.
// Output dtype follows input dtype: fp32 if isf else bf16. [N][2][48].
// ---------------------------------------------------------------------------
__global__ __launch_bounds__(256) void heads_kernel(
    const unsigned short* __restrict__ ws, void* __restrict__ out)
{
    __shared__ unsigned short afrag[4][4][4][16][8];  // [wave][ktile][quad][m][j]
    const int tid  = threadIdx.x;
    const int wave = tid >> 6, lane = tid & 63;
    const int quad = lane >> 4, m16 = lane & 15;
    const int r0   = blockIdx.x * 64 + wave * 16;
    const int isf  = ((const int*)ws)[0];

    const unsigned short* HW    = ws + OFF_HW;
    const float*          BB    = (const float*)(ws + OFF_BIASH);
    const unsigned short* featH = ws + OFF_FEAT;
    const unsigned short* featL = featH + 8192 * 128;

    short8 fh[4], fl[4];
#pragma unroll
    for (int kt = 0; kt < 4; ++kt) {
        size_t o = (size_t)(r0 + m16) * 128 + kt * 32 + quad * 8;
        fh[kt] = *(const short8*)&featH[o];
        fl[kt] = *(const short8*)&featL[o];
    }

    for (int head = 0; head < 2; ++head) {
        const unsigned short* W1 = HW + (head ? 21504 : 0);
        const unsigned short* W2 = W1 + 12288;
        const unsigned short* W3 = W2 + 6144;
        const float* b1 = BB + head * 208;
        const float* b2 = b1 + 96;
        const float* b3 = b2 + 64;

        // L1: K=128, O=96, relu
        f32x4 a1[6] = {{0,0,0,0},{0,0,0,0},{0,0,0,0},{0,0,0,0},{0,0,0,0},{0,0,0,0}};
#pragma unroll
        for (int kt = 0; kt < 4; ++kt)
#pragma unroll
            for (int nt = 0; nt < 6; ++nt) {
                short8 bw = *(const short8*)
                    &W1[(nt * 16 + m16) * 128 + kt * 32 + quad * 8];
                a1[nt] = MFMA(fh[kt], bw, a1[nt]);
                a1[nt] = MFMA(fl[kt], bw, a1[nt]);
            }
#pragma unroll
        for (int nt = 0; nt < 6; ++nt) {
            int u = nt * 16 + m16;
            float bv = b1[u];
#pragma unroll
            for (int r = 0; r < 4; ++r) {
                float v = a1[nt][r] + bv;
                v = v > 0.f ? v : 0.f;
                afrag[wave][u >> 5][(u >> 3) & 3][quad * 4 + r][u & 7] = f2b(v);
            }
        }
        __syncthreads();

        // L2: K=96, O=64, relu
        f32x4 a2[4] = {{0,0,0,0},{0,0,0,0},{0,0,0,0},{0,0,0,0}};
#pragma unroll
        for (int kt = 0; kt < 3; ++kt) {
            short8 a = *(const short8*)&afrag[wave][kt][quad][m16][0];
#pragma unroll
            for (int nt = 0; nt < 4; ++nt) {
                short8 bw = *(const short8*)
                    &W2[(nt * 16 + m16) * 96 + kt * 32 + quad * 8];
                a2[nt] = MFMA(a, bw, a2[nt]);
            }
        }
        __syncthreads();
#pragma unroll
        for (int nt = 0; nt < 4; ++nt) {
            int u = nt * 16 + m16;
            float bv = b2[u];
#pragma unroll
            for (int r = 0; r < 4; ++r) {
                float v = a2[nt][r] + bv;
                v = v > 0.f ? v : 0.f;
                afrag[wave][u >> 5][(u >> 3) & 3][quad * 4 + r][u & 7] = f2b(v);
            }
        }
        __syncthreads();

        // L3: K=64, O=48, no relu -> out[n][head][u], dtype per isf
        f32x4 a3[3] = {{0,0,0,0},{0,0,0,0},{0,0,0,0}};
#pragma unroll
        for (int kt = 0; kt < 2; ++kt) {
            short8 a = *(const short8*)&afrag[wave][kt][quad][m16][0];
#pragma unroll
            for (int nt = 0; nt < 3; ++nt) {
                short8 bw = *(const short8*)
                    &W3[(nt * 16 + m16) * 64 + kt * 32 + quad * 8];
                a3[nt] = MFMA(a, bw, a3[nt]);
            }
        }
#pragma unroll
        for (int nt = 0; nt < 3; ++nt) {
            int u = nt * 16 + m16;
            float bv = b3[u];
#pragma unroll
            for (int r = 0; r < 4; ++r) {
                int row = quad * 4 + r;
                size_t idx = (size_t)(r0 + row) * 96 + head * 48 + u;
                float v = a3[nt][r] + bv;
                if (isf) ((float*)out)[idx] = v;
                else     ((unsigned short*)out)[idx] = f2b(v);
            }
        }
        __syncthreads();
    }
}

// ---------------------------------------------------------------------------
extern "C" void kernel_launch(void* const* d_in, const int* in_sizes, int n_in,
                              void* d_out, int out_size, void* d_ws, size_t ws_size,
                              hipStream_t stream)
{
    unsigned short* ws = (unsigned short*)d_ws;

    detect_kernel<<<1, 256, 0, stream>>>((const unsigned short*)d_in[0], (int*)d_ws);
    prep_kernel<<<64, 256, 0, stream>>>(
        d_in[2], d_in[3], d_in[4], d_in[5],
        d_in[6], d_in[7], d_in[8], d_in[9],
        d_in[10], d_in[11], d_in[12], d_in[13], d_in[14], d_in[15],
        d_in[16], d_in[17], d_in[18], d_in[19], d_in[20], d_in[21],
        ws);
    lstm_kernel<<<1024, 256, 0, stream>>>(d_in[0], d_in[1], ws);
    heads_kernel<<<128, 256, 0, stream>>>(ws, d_out);
}